// Round 1
// baseline (1117.685 us; speedup 1.0000x reference)
//
#include <hip/hip_runtime.h>
#include <stdint.h>

// Transformer encoder: B=32 S=512 D=512 H=8 L=4 FFN=1024 DH=64
#define NB 32
#define NS 512
#define ND 512
#define NH 8
#define NL 4
#define NF 1024
#define NDH 64
#define NM (NB*NS)          // 16384 rows
#define WLSTRIDE 2097152    // bf16 elems per layer in transposed weight pack

typedef __attribute__((ext_vector_type(8))) short bf16x8;
typedef __attribute__((ext_vector_type(4))) float f32x4;

__device__ __forceinline__ short f2bf(float f) {
    union { float f; uint32_t u; } v; v.f = f;
    uint32_t r = (v.u + 0x7FFFu + ((v.u >> 16) & 1u)) >> 16;
    return (short)r;
}
__device__ __forceinline__ float bf2f(short s) {
    union { uint32_t u; float f; } v; v.u = ((uint32_t)(uint16_t)s) << 16;
    return v.f;
}
__device__ __forceinline__ f32x4 mfma16(bf16x8 a, bf16x8 b, f32x4 c) {
    return __builtin_amdgcn_mfma_f32_16x16x32_bf16(a, b, c, 0, 0, 0);
}
__device__ __forceinline__ void gld16(const void* g, void* l) {
    __builtin_amdgcn_global_load_lds(
        (const __attribute__((address_space(1))) void*)g,
        (__attribute__((address_space(3))) void*)l, 16, 0, 0);
}

// ---------------- weight convert + transpose: W(K,N) f32 -> Wt(N,K) bf16 ----------
__global__ __launch_bounds__(256) void convT_k(const float* __restrict__ src,
        short* __restrict__ dst, int K, int N, int woff, int total)
{
    int i = blockIdx.x * 256 + threadIdx.x;
    if (i >= total) return;
    int per = K * N;
    int l = i / per, r = i - l * per;
    int n = r / K, k = r - n * K;
    dst[(size_t)l * WLSTRIDE + woff + r] = f2bf(src[(size_t)l * per + (size_t)k * N + n]);
}

// ---------------- x + pe -> bf16 ----------------
__global__ __launch_bounds__(256) void addpe_k(const float* __restrict__ x,
        const float* __restrict__ pe, short* __restrict__ X)
{
    size_t i = ((size_t)blockIdx.x * 256 + threadIdx.x) * 8;
    size_t sd = i % (size_t)(NS * ND);
    f32x4 a0 = *(const f32x4*)(x + i);
    f32x4 a1 = *(const f32x4*)(x + i + 4);
    f32x4 p0 = *(const f32x4*)(pe + sd);
    f32x4 p1 = *(const f32x4*)(pe + sd + 4);
    bf16x8 r;
    #pragma unroll
    for (int j = 0; j < 4; j++) { r[j] = f2bf(a0[j] + p0[j]); r[4 + j] = f2bf(a1[j] + p1[j]); }
    *(bf16x8*)(X + i) = r;
}

// ---------------- GEMM: C(M,N) = A(M,K)bf16 @ Bt(N,K)bf16^T + bias -----------------
// EPI 0: bf16 out (bias). EPI 1: bf16 out (bias+relu). EPI 2: f32 out (bias + bf16 residual)
template<int EPI>
__global__ __launch_bounds__(256) void gemm_bt(
        const short* __restrict__ A, const short* __restrict__ Bt,
        const float* __restrict__ bias, const short* __restrict__ res,
        void* __restrict__ Cout, int M, int N, int K)
{
    __shared__ __align__(16) short Al[4096];   // [128][32] (swizzled, bits4-5 ^= bits7-8)
    __shared__ __align__(16) short Bl[4096];
    const int tid = threadIdx.x;
    const int wid = tid >> 6, lane = tid & 63;
    const int m0 = blockIdx.y * 128, n0 = blockIdx.x * 128;
    const int wr = wid >> 1, wc = wid & 1;

    f32x4 acc[4][4];
    f32x4 zz = {0.f, 0.f, 0.f, 0.f};
    #pragma unroll
    for (int i = 0; i < 4; i++)
        #pragma unroll
        for (int j = 0; j < 4; j++) acc[i][j] = zz;

    const char* Ab = (const char*)A;
    const char* Bb = (const char*)Bt;
    const size_t rk = (size_t)K * 2;

    for (int k0 = 0; k0 < K; k0 += 32) {
        __syncthreads();
        #pragma unroll
        for (int c = 0; c < 2; c++) {
            int p = c * 4096 + wid * 1024 + lane * 16;
            int sl = (p & 63) ^ (((p >> 7) & 3) << 4);
            gld16(Ab + (size_t)(m0 + (p >> 6)) * rk + (size_t)k0 * 2 + sl,
                  (char*)Al + c * 4096 + wid * 1024);
            gld16(Bb + (size_t)(n0 + (p >> 6)) * rk + (size_t)k0 * 2 + sl,
                  (char*)Bl + c * 4096 + wid * 1024);
        }
        __syncthreads();
        bf16x8 af[4], bfr[4];
        #pragma unroll
        for (int mf = 0; mf < 4; mf++) {
            int off = (wr * 64 + mf * 16 + (lane & 15)) * 64 + ((lane >> 4) * 16);
            off ^= ((off >> 7) & 3) << 4;
            af[mf] = *(const bf16x8*)((const char*)Al + off);
        }
        #pragma unroll
        for (int nf = 0; nf < 4; nf++) {
            int off = (wc * 64 + nf * 16 + (lane & 15)) * 64 + ((lane >> 4) * 16);
            off ^= ((off >> 7) & 3) << 4;
            bfr[nf] = *(const bf16x8*)((const char*)Bl + off);
        }
        #pragma unroll
        for (int mf = 0; mf < 4; mf++)
            #pragma unroll
            for (int nf = 0; nf < 4; nf++)
                acc[mf][nf] = mfma16(af[mf], bfr[nf], acc[mf][nf]);
    }

    #pragma unroll
    for (int mf = 0; mf < 4; mf++) {
        #pragma unroll
        for (int nf = 0; nf < 4; nf++) {
            int col = n0 + wc * 64 + nf * 16 + (lane & 15);
            float bi = bias[col];
            #pragma unroll
            for (int r = 0; r < 4; r++) {
                int row = m0 + wr * 64 + mf * 16 + ((lane >> 4) << 2) + r;
                float v = acc[mf][nf][r] + bi;
                if (EPI == 0) {
                    ((short*)Cout)[(size_t)row * N + col] = f2bf(v);
                } else if (EPI == 1) {
                    ((short*)Cout)[(size_t)row * N + col] = f2bf(fmaxf(v, 0.f));
                } else {
                    v += bf2f(res[(size_t)row * N + col]);
                    ((float*)Cout)[(size_t)row * N + col] = v;
                }
            }
        }
    }
}

// ---------------- flash attention on flat (B*H=256, S=512, DH=64) view -------------
__global__ __launch_bounds__(256) void attn_k(
        const short* __restrict__ Q, const short* __restrict__ Kb,
        const short* __restrict__ Vb, short* __restrict__ ctx)
{
    __shared__ __align__(16) short Kl[4096];   // [64 kv][64 dh] swizzled (^ (row&7)<<4 on bytes)
    __shared__ __align__(16) short Vt[4096];   // [64 dh][64 kv] swizzled
    __shared__ __align__(16) short Pl[4096];   // [64 q ][64 kv] swizzled
    const int tid = threadIdx.x, wid = tid >> 6, lane = tid & 63;
    const int bh = blockIdx.y, q0 = blockIdx.x * 64;
    const size_t base = (size_t)bh * NS * NDH;

    // Q fragments in registers: wave wid owns q rows q0+wid*16 .. +16
    bf16x8 qa[2];
    #pragma unroll
    for (int ks = 0; ks < 2; ks++)
        qa[ks] = *(const bf16x8*)(Q + base + (size_t)(q0 + wid * 16 + (lane & 15)) * NDH
                                  + ks * 32 + ((lane >> 4) * 8));

    float m[4], lsum[4];
    f32x4 o[4];
    f32x4 zz = {0.f, 0.f, 0.f, 0.f};
    #pragma unroll
    for (int r = 0; r < 4; r++) { m[r] = -1e30f; lsum[r] = 0.f; }
    #pragma unroll
    for (int nf = 0; nf < 4; nf++) o[nf] = zz;

    const int kv = tid & 63, dh0 = (tid >> 6) * 16;

    for (int kt = 0; kt < 8; kt++) {
        // V tile to regs (global, issued before barrier)
        const short* Vsrc = Vb + base + (size_t)kt * 64 * NDH;
        bf16x8 v0 = *(const bf16x8*)(Vsrc + kv * 64 + dh0);
        bf16x8 v1 = *(const bf16x8*)(Vsrc + kv * 64 + dh0 + 8);
        __syncthreads();   // prior iteration's LDS reads done
        // K tile: contiguous 8KB, global_load_lds with pre-swizzled source
        const char* Ksrc = (const char*)(Kb + base + (size_t)kt * 64 * NDH);
        #pragma unroll
        for (int c = 0; c < 2; c++) {
            int p = c * 4096 + wid * 1024 + lane * 16;
            int sp = p ^ (((p >> 7) & 7) << 4);
            gld16(Ksrc + sp, (char*)Kl + c * 4096 + wid * 1024);
        }
        // V transposed into LDS
        #pragma unroll
        for (int j = 0; j < 16; j++) {
            int dh = dh0 + j;
            int bo = (dh * 128 + kv * 2) ^ ((dh & 7) << 4);
            *(short*)((char*)Vt + bo) = (j < 8) ? v0[j] : v1[j - 8];
        }
        __syncthreads();   // staging complete

        // S = Q @ K^T  (per wave: 16 q x 64 kv)
        f32x4 sc[4];
        #pragma unroll
        for (int nf = 0; nf < 4; nf++) sc[nf] = zz;
        #pragma unroll
        for (int ks = 0; ks < 2; ks++) {
            #pragma unroll
            for (int nf = 0; nf < 4; nf++) {
                int kvr = nf * 16 + (lane & 15);
                int bo = (kvr * 128 + ks * 64 + ((lane >> 4) * 16)) ^ ((kvr & 7) << 4);
                bf16x8 kf = *(const bf16x8*)((const char*)Kl + bo);
                sc[nf] = mfma16(qa[ks], kf, sc[nf]);
            }
        }
        #pragma unroll
        for (int nf = 0; nf < 4; nf++)
            #pragma unroll
            for (int r = 0; r < 4; r++) sc[nf][r] *= 0.125f;   // 1/sqrt(64)

        // online softmax (row = (lane>>4)*4 + r within wave's 16 rows)
        #pragma unroll
        for (int r = 0; r < 4; r++) {
            float rm = fmaxf(fmaxf(sc[0][r], sc[1][r]), fmaxf(sc[2][r], sc[3][r]));
            rm = fmaxf(rm, __shfl_xor(rm, 1));
            rm = fmaxf(rm, __shfl_xor(rm, 2));
            rm = fmaxf(rm, __shfl_xor(rm, 4));
            rm = fmaxf(rm, __shfl_xor(rm, 8));
            float mn = fmaxf(m[r], rm);
            float corr = __expf(m[r] - mn);
            m[r] = mn;
            float rs = 0.f;
            #pragma unroll
            for (int nf = 0; nf < 4; nf++) {
                float pv = __expf(sc[nf][r] - mn);
                sc[nf][r] = pv;
                rs += pv;
            }
            rs += __shfl_xor(rs, 1);
            rs += __shfl_xor(rs, 2);
            rs += __shfl_xor(rs, 4);
            rs += __shfl_xor(rs, 8);
            lsum[r] = lsum[r] * corr + rs;
            #pragma unroll
            for (int nf = 0; nf < 4; nf++) o[nf][r] *= corr;
            // P -> LDS (bf16, swizzled)
            int qr = wid * 16 + ((lane >> 4) << 2) + r;
            #pragma unroll
            for (int nf = 0; nf < 4; nf++) {
                int bo = (qr * 128 + (nf * 16 + (lane & 15)) * 2) ^ ((qr & 7) << 4);
                *(short*)((char*)Pl + bo) = f2bf(sc[nf][r]);
            }
        }
        __syncthreads();   // P visible (also orders in-wave ds_write -> ds_read)

        // O += P @ V
        #pragma unroll
        for (int ks = 0; ks < 2; ks++) {
            int qr = wid * 16 + (lane & 15);
            int bo = (qr * 128 + ks * 64 + ((lane >> 4) * 16)) ^ ((qr & 7) << 4);
            bf16x8 pa = *(const bf16x8*)((const char*)Pl + bo);
            #pragma unroll
            for (int nf = 0; nf < 4; nf++) {
                int dh = nf * 16 + (lane & 15);
                int bo2 = (dh * 128 + ks * 64 + ((lane >> 4) * 16)) ^ ((dh & 7) << 4);
                bf16x8 vf = *(const bf16x8*)((const char*)Vt + bo2);
                o[nf] = mfma16(pa, vf, o[nf]);
            }
        }
    }

    #pragma unroll
    for (int nf = 0; nf < 4; nf++)
        #pragma unroll
        for (int r = 0; r < 4; r++) {
            int qr = q0 + wid * 16 + ((lane >> 4) << 2) + r;
            int dh = nf * 16 + (lane & 15);
            ctx[base + (size_t)qr * NDH + dh] = f2bf(o[nf][r] / lsum[r]);
        }
}

// ---------------- LayerNorm over D=512; one wave per row ----------------
template<int OUTF32>
__global__ __launch_bounds__(256) void ln_k(
        const float* __restrict__ pre, const float* __restrict__ g,
        const float* __restrict__ b, void* __restrict__ out)
{
    int row = blockIdx.x * 4 + (threadIdx.x >> 6);
    int lane = threadIdx.x & 63;
    const float* x = pre + (size_t)row * ND + lane * 8;
    f32x4 a0 = *(const f32x4*)x;
    f32x4 a1 = *(const f32x4*)(x + 4);
    float s = 0.f, sq = 0.f;
    #pragma unroll
    for (int j = 0; j < 4; j++) { s += a0[j]; sq += a0[j] * a0[j]; s += a1[j]; sq += a1[j] * a1[j]; }
    #pragma unroll
    for (int d = 1; d < 64; d <<= 1) { s += __shfl_xor(s, d); sq += __shfl_xor(sq, d); }
    float mean = s * (1.f / ND);
    float var = sq * (1.f / ND) - mean * mean;
    float rstd = rsqrtf(var + 1e-5f);
    const float* gp = g + lane * 8;
    const float* bp = b + lane * 8;
    if (OUTF32) {
        float* op = (float*)out + (size_t)row * ND + lane * 8;
        f32x4 r0, r1;
        #pragma unroll
        for (int j = 0; j < 4; j++) {
            r0[j] = (a0[j] - mean) * rstd * gp[j] + bp[j];
            r1[j] = (a1[j] - mean) * rstd * gp[4 + j] + bp[4 + j];
        }
        *(f32x4*)op = r0;
        *(f32x4*)(op + 4) = r1;
    } else {
        bf16x8 rr;
        #pragma unroll
        for (int j = 0; j < 4; j++) {
            rr[j]     = f2bf((a0[j] - mean) * rstd * gp[j] + bp[j]);
            rr[4 + j] = f2bf((a1[j] - mean) * rstd * gp[4 + j] + bp[4 + j]);
        }
        *(bf16x8*)((short*)out + (size_t)row * ND + lane * 8) = rr;
    }
}

extern "C" void kernel_launch(void* const* d_in, const int* in_sizes, int n_in,
                              void* d_out, int out_size, void* d_ws, size_t ws_size,
                              hipStream_t stream)
{
    (void)in_sizes; (void)n_in; (void)out_size; (void)ws_size;
    const float* x   = (const float*)d_in[0];
    const float* pe  = (const float*)d_in[1];
    const float* Wq  = (const float*)d_in[2];
    const float* bq  = (const float*)d_in[3];
    const float* Wk  = (const float*)d_in[4];
    const float* bk  = (const float*)d_in[5];
    const float* Wv  = (const float*)d_in[6];
    const float* bv  = (const float*)d_in[7];
    const float* Wo  = (const float*)d_in[8];
    const float* bo  = (const float*)d_in[9];
    const float* g1  = (const float*)d_in[10];
    const float* be1 = (const float*)d_in[11];
    const float* W1  = (const float*)d_in[12];
    const float* b1  = (const float*)d_in[13];
    const float* W2  = (const float*)d_in[14];
    const float* b2  = (const float*)d_in[15];
    const float* g2  = (const float*)d_in[16];
    const float* be2 = (const float*)d_in[17];

    char* ws = (char*)d_ws;
    short* WT = (short*)(ws);                       // 16 MiB transposed bf16 weights
    short* XB = (short*)(ws + (size_t)16  * 1048576);  // activation bf16
    short* QB = (short*)(ws + (size_t)32  * 1048576);  // Q   (aliased: a post-LN1)
    short* KB = (short*)(ws + (size_t)48  * 1048576);  // K   (aliased: h low half)
    short* VB = (short*)(ws + (size_t)64  * 1048576);  // V   (aliased: h high half)
    short* CT = (short*)(ws + (size_t)80  * 1048576);  // attention context
    float* PR = (float*)(ws + (size_t)96  * 1048576);  // pre-LN f32 (32 MiB)
    short* AB = QB;
    short* HB = KB;

    // weights: convert + transpose (per launch; graph-capture safe)
    convT_k<<<dim3((NL*ND*ND + 255) / 256), 256, 0, stream>>>(Wq, WT, ND, ND, 0,       NL*ND*ND);
    convT_k<<<dim3((NL*ND*ND + 255) / 256), 256, 0, stream>>>(Wk, WT, ND, ND, 262144,  NL*ND*ND);
    convT_k<<<dim3((NL*ND*ND + 255) / 256), 256, 0, stream>>>(Wv, WT, ND, ND, 524288,  NL*ND*ND);
    convT_k<<<dim3((NL*ND*ND + 255) / 256), 256, 0, stream>>>(Wo, WT, ND, ND, 786432,  NL*ND*ND);
    convT_k<<<dim3((NL*ND*NF + 255) / 256), 256, 0, stream>>>(W1, WT, ND, NF, 1048576, NL*ND*NF);
    convT_k<<<dim3((NL*NF*ND + 255) / 256), 256, 0, stream>>>(W2, WT, NF, ND, 1572864, NL*NF*ND);

    addpe_k<<<dim3(4096), 256, 0, stream>>>(x, pe, XB);

    for (int l = 0; l < NL; l++) {
        const short* wl = WT + (size_t)l * WLSTRIDE;
        gemm_bt<0><<<dim3(4, 128), 256, 0, stream>>>(XB, wl,          bq + l*ND, nullptr, QB, NM, ND, ND);
        gemm_bt<0><<<dim3(4, 128), 256, 0, stream>>>(XB, wl + 262144, bk + l*ND, nullptr, KB, NM, ND, ND);
        gemm_bt<0><<<dim3(4, 128), 256, 0, stream>>>(XB, wl + 524288, bv + l*ND, nullptr, VB, NM, ND, ND);
        attn_k<<<dim3(8, 256), 256, 0, stream>>>(QB, KB, VB, CT);
        gemm_bt<2><<<dim3(4, 128), 256, 0, stream>>>(CT, wl + 786432, bo + l*ND, XB, PR, NM, ND, ND);
        ln_k<0><<<dim3(4096), 256, 0, stream>>>(PR, g1 + l*ND, be1 + l*ND, AB);
        gemm_bt<1><<<dim3(8, 128), 256, 0, stream>>>(AB, wl + 1048576, b1 + l*NF, nullptr, HB, NM, NF, ND);
        gemm_bt<2><<<dim3(4, 128), 256, 0, stream>>>(HB, wl + 1572864, b2 + l*ND, AB, PR, NM, ND, NF);
        if (l < NL - 1)
            ln_k<0><<<dim3(4096), 256, 0, stream>>>(PR, g2 + l*ND, be2 + l*ND, XB);
        else
            ln_k<1><<<dim3(4096), 256, 0, stream>>>(PR, g2 + l*ND, be2 + l*ND, d_out);
    }
}

// Round 3
// 908.076 us; speedup vs baseline: 1.2308x; 1.2308x over previous
//
#include <hip/hip_runtime.h>
#include <stdint.h>

// Transformer encoder: B=32 S=512 D=512 H=8 L=4 FFN=1024 DH=64
#define NB 32
#define NS 512
#define ND 512
#define NH 8
#define NL 4
#define NF 1024
#define NDH 64
#define NM (NB*NS)          // 16384 rows
#define WLSTRIDE 2097152    // bf16 elems per layer in transposed weight pack

typedef __attribute__((ext_vector_type(8))) short bf16x8;
typedef __attribute__((ext_vector_type(4))) float f32x4;

__device__ __forceinline__ short f2bf(float f) {
    union { float f; uint32_t u; } v; v.f = f;
    uint32_t r = (v.u + 0x7FFFu + ((v.u >> 16) & 1u)) >> 16;
    return (short)r;
}
__device__ __forceinline__ float bf2f(short s) {
    union { uint32_t u; float f; } v; v.u = ((uint32_t)(uint16_t)s) << 16;
    return v.f;
}
__device__ __forceinline__ f32x4 mfma16(bf16x8 a, bf16x8 b, f32x4 c) {
    return __builtin_amdgcn_mfma_f32_16x16x32_bf16(a, b, c, 0, 0, 0);
}
__device__ __forceinline__ void gld16(const void* g, void* l) {
    __builtin_amdgcn_global_load_lds(
        (const __attribute__((address_space(1))) void*)g,
        (__attribute__((address_space(3))) void*)l, 16, 0, 0);
}
// bijective XCD-chunked swizzle (m204); requires gx*gy % 8 == 0
__device__ __forceinline__ void xcd_swz(int& bx, int& by, int gx, int gy) {
    int n = gx * gy;
    int f = by * gx + bx;
    int q = n >> 3;
    int xcd = f & 7, idx = f >> 3;
    int s = xcd * q + idx;
    bx = s % gx; by = s / gx;
}

// ---------------- weight convert + transpose: W(K,N) f32 -> Wt(N,K) bf16 ----------
__global__ __launch_bounds__(256) void convT_k(const float* __restrict__ src,
        short* __restrict__ dst, int K, int N, int woff, int total)
{
    int i = blockIdx.x * 256 + threadIdx.x;
    if (i >= total) return;
    int per = K * N;
    int l = i / per, r = i - l * per;
    int n = r / K, k = r - n * K;
    dst[(size_t)l * WLSTRIDE + woff + r] = f2bf(src[(size_t)l * per + (size_t)k * N + n]);
}

// ---------------- bias pack: [bq|bk|bv] per layer -> (L,1536) f32 ----------------
__global__ __launch_bounds__(256) void biaspack_k(const float* __restrict__ bq,
        const float* __restrict__ bk, const float* __restrict__ bv, float* __restrict__ out)
{
    int i = blockIdx.x * 256 + threadIdx.x;
    if (i >= NL * 1536) return;
    int l = i / 1536, j = i - l * 1536;
    float v = (j < 512) ? bq[l * 512 + j] : (j < 1024) ? bk[l * 512 + j - 512]
                                                       : bv[l * 512 + j - 1024];
    out[i] = v;
}

// ---------------- x + pe -> bf16 ----------------
__global__ __launch_bounds__(256) void addpe_k(const float* __restrict__ x,
        const float* __restrict__ pe, short* __restrict__ X)
{
    size_t i = ((size_t)blockIdx.x * 256 + threadIdx.x) * 8;
    size_t sd = i % (size_t)(NS * ND);
    f32x4 a0 = *(const f32x4*)(x + i);
    f32x4 a1 = *(const f32x4*)(x + i + 4);
    f32x4 p0 = *(const f32x4*)(pe + sd);
    f32x4 p1 = *(const f32x4*)(pe + sd + 4);
    bf16x8 r;
    #pragma unroll
    for (int j = 0; j < 4; j++) { r[j] = f2bf(a0[j] + p0[j]); r[4 + j] = f2bf(a1[j] + p1[j]); }
    *(bf16x8*)(X + i) = r;
}

// ---------------- GEMM: C(M,N) = A(M,K)bf16 @ Bt(N,K)bf16^T + bias, BK=64 ----------
// EPI 0: QKV split -> C0/C1/C2 bf16 (stride 512) by col segment
// EPI 1: bf16 out (bias+relu), stride N. EPI 2: f32 out (bias + bf16 residual), stride N.
template<int EPI>
__global__ __launch_bounds__(256) void gemm_bt(
        const short* __restrict__ A, const short* __restrict__ Bt,
        const float* __restrict__ bias, const short* __restrict__ res,
        void* __restrict__ C0, void* __restrict__ C1, void* __restrict__ C2,
        int M, int N, int K)
{
    __shared__ __align__(16) short Al[8192];   // [128][64] bf16, XOR-swizzled
    __shared__ __align__(16) short Bl[8192];
    const int tid = threadIdx.x;
    const int wid = tid >> 6, lane = tid & 63;
    int bx = blockIdx.x, by = blockIdx.y;
    xcd_swz(bx, by, gridDim.x, gridDim.y);
    const int m0 = by * 128, n0 = bx * 128;
    const int wr = wid >> 1, wc = wid & 1;

    f32x4 acc[4][4];
    f32x4 zz = {0.f, 0.f, 0.f, 0.f};
    #pragma unroll
    for (int i = 0; i < 4; i++)
        #pragma unroll
        for (int j = 0; j < 4; j++) acc[i][j] = zz;

    const size_t rk = (size_t)K * 2;
    const char* Ab = (const char*)A + (size_t)m0 * rk;
    const char* Bb = (const char*)Bt + (size_t)n0 * rk;

    // per-thread staging coords (4 chunks of 16B per matrix)
    int srow[4], scol[4];
    #pragma unroll
    for (int c = 0; c < 4; c++) {
        int p = c * 4096 + tid * 16;
        int l = p ^ (((p >> 7) & 7) << 4);
        srow[c] = l >> 7;  scol[c] = l & 127;
    }

    for (int k0 = 0; k0 < K; k0 += 64) {
        __syncthreads();
        #pragma unroll
        for (int c = 0; c < 4; c++)
            gld16(Ab + (size_t)srow[c] * rk + (size_t)k0 * 2 + scol[c],
                  (char*)Al + c * 4096 + wid * 1024);
        #pragma unroll
        for (int c = 0; c < 4; c++)
            gld16(Bb + (size_t)srow[c] * rk + (size_t)k0 * 2 + scol[c],
                  (char*)Bl + c * 4096 + wid * 1024);
        __syncthreads();
        #pragma unroll
        for (int ks = 0; ks < 2; ks++) {
            bf16x8 af[4], bfr[4];
            #pragma unroll
            for (int mf = 0; mf < 4; mf++) {
                int row = wr * 64 + mf * 16 + (lane & 15);
                int off = (row * 128 + ks * 64 + ((lane >> 4) * 16)) ^ ((row & 7) << 4);
                af[mf] = *(const bf16x8*)((const char*)Al + off);
            }
            #pragma unroll
            for (int nf = 0; nf < 4; nf++) {
                int row = wc * 64 + nf * 16 + (lane & 15);
                int off = (row * 128 + ks * 64 + ((lane >> 4) * 16)) ^ ((row & 7) << 4);
                bfr[nf] = *(const bf16x8*)((const char*)Bl + off);
            }
            #pragma unroll
            for (int mf = 0; mf < 4; mf++)
                #pragma unroll
                for (int nf = 0; nf < 4; nf++)
                    acc[mf][nf] = mfma16(af[mf], bfr[nf], acc[mf][nf]);
        }
    }

    // output routing
    void* outp;
    int colbase, ostride;
    if (EPI == 0) {
        int seg = n0 >> 9;
        outp = (seg == 0) ? C0 : (seg == 1) ? C1 : C2;
        colbase = n0 & 511; ostride = 512;
    } else {
        outp = C0; colbase = n0; ostride = N;
    }

    #pragma unroll
    for (int mf = 0; mf < 4; mf++) {
        #pragma unroll
        for (int nf = 0; nf < 4; nf++) {
            int colg = n0 + wc * 64 + nf * 16 + (lane & 15);       // bias index
            int col  = colbase + wc * 64 + nf * 16 + (lane & 15);  // output col
            float bi = bias[colg];
            #pragma unroll
            for (int r = 0; r < 4; r++) {
                int row = m0 + wr * 64 + mf * 16 + ((lane >> 4) << 2) + r;
                float v = acc[mf][nf][r] + bi;
                if (EPI == 0) {
                    ((short*)outp)[(size_t)row * 512 + col] = f2bf(v);
                } else if (EPI == 1) {
                    ((short*)outp)[(size_t)row * ostride + col] = f2bf(fmaxf(v, 0.f));
                } else {
                    v += bf2f(res[(size_t)row * ostride + col]);
                    ((float*)outp)[(size_t)row * ostride + col] = v;
                }
            }
        }
    }
}

// ---------------- V transpose (flat-group view): VB(g,kv,dh) -> VT(g,dh,kv) --------
__global__ __launch_bounds__(256) void vtrans_k(const short* __restrict__ V,
        short* __restrict__ VT)
{
    __shared__ short T[64][65];
    const int tid = threadIdx.x;
    const int r0 = blockIdx.x * 64, g = blockIdx.y;
    const size_t base = (size_t)g * 32768;
    #pragma unroll
    for (int rep = 0; rep < 2; rep++) {
        int chunk = rep * 256 + tid;
        int sr = chunk >> 3, c8 = (chunk & 7) * 8;
        bf16x8 v = *(const bf16x8*)(V + base + (size_t)(r0 + sr) * 64 + c8);
        #pragma unroll
        for (int j = 0; j < 8; j++) T[sr][c8 + j] = v[j];
    }
    __syncthreads();
    #pragma unroll
    for (int rep = 0; rep < 2; rep++) {
        int chunk = rep * 256 + tid;
        int dh = chunk >> 3, c8 = (chunk & 7) * 8;
        bf16x8 w;
        #pragma unroll
        for (int j = 0; j < 8; j++) w[j] = T[c8 + j][dh];
        *(bf16x8*)(VT + base + (size_t)dh * 512 + r0 + c8) = w;
    }
}

// ---------------- flash attention on flat (256, 512, 64) groups, QBLK=128 ----------
// Q,K: (g,r,c) flat buffers; V from VT(g,dh,kv); out ctx flat (g,r,c)
__global__ __launch_bounds__(256) void attn_k(
        const short* __restrict__ Q, const short* __restrict__ Kb,
        const short* __restrict__ VT, short* __restrict__ ctx)
{
    __shared__ __align__(16) short Kl[4096];   // [64 kv][64 dh] swizzled
    __shared__ __align__(16) short Vl[4096];   // [64 dh][64 kv] swizzled
    __shared__ __align__(16) short Pl[8192];   // [128 q][64 kv] swizzled (wave-private quarters)
    const int tid = threadIdx.x, wid = tid >> 6, lane = tid & 63;
    int bx = blockIdx.x, by = blockIdx.y;
    xcd_swz(bx, by, gridDim.x, gridDim.y);
    const int g = by, q0 = bx * 128;
    const size_t base = (size_t)g * 32768;
    const float C = 0.18033688f;               // 0.125 * log2(e)

    // Q fragments: wave wid owns q rows q0+wid*32 .. +32 (2 frags of 16)
    bf16x8 qa[2][2];
    #pragma unroll
    for (int qf = 0; qf < 2; qf++)
        #pragma unroll
        for (int ks = 0; ks < 2; ks++)
            qa[qf][ks] = *(const bf16x8*)(Q + base
                + (size_t)(q0 + wid * 32 + qf * 16 + (lane & 15)) * 64
                + ks * 32 + ((lane >> 4) * 8));

    f32x4 o[2][4];
    float ps[2][4];
    f32x4 zz = {0.f, 0.f, 0.f, 0.f};
    #pragma unroll
    for (int qf = 0; qf < 2; qf++) {
        #pragma unroll
        for (int nf = 0; nf < 4; nf++) o[qf][nf] = zz;
        #pragma unroll
        for (int r = 0; r < 4; r++) ps[qf][r] = 0.f;
    }

    const char* Kbase = (const char*)(Kb + base);   // K tile kt: contiguous 8KB at kt*8192
    const char* Vbase = (const char*)(VT + base);   // V tile: rows dh (1024B stride), cols kt*128B

    // staging coords (2 chunks per matrix per thread)
    int srow[2], scol[2];
    #pragma unroll
    for (int c = 0; c < 2; c++) {
        int p = c * 4096 + tid * 16;
        int l = p ^ (((p >> 7) & 7) << 4);
        srow[c] = l >> 7;  scol[c] = l & 127;
    }

    for (int kt = 0; kt < 8; kt++) {
        __syncthreads();
        #pragma unroll
        for (int c = 0; c < 2; c++) {
            int p = c * 4096 + tid * 16;
            int sp = p ^ (((p >> 7) & 7) << 4);
            gld16(Kbase + (size_t)kt * 8192 + sp, (char*)Kl + c * 4096 + wid * 1024);
        }
        #pragma unroll
        for (int c = 0; c < 2; c++)
            gld16(Vbase + (size_t)srow[c] * 1024 + kt * 128 + scol[c],
                  (char*)Vl + c * 4096 + wid * 1024);
        __syncthreads();

        // S = Q @ K^T
        f32x4 sc[2][4];
        #pragma unroll
        for (int qf = 0; qf < 2; qf++)
            #pragma unroll
            for (int nf = 0; nf < 4; nf++) sc[qf][nf] = zz;
        #pragma unroll
        for (int ks = 0; ks < 2; ks++) {
            #pragma unroll
            for (int nf = 0; nf < 4; nf++) {
                int kvr = nf * 16 + (lane & 15);
                int bo = (kvr * 128 + ks * 64 + ((lane >> 4) * 16)) ^ ((kvr & 7) << 4);
                bf16x8 kf = *(const bf16x8*)((const char*)Kl + bo);
                #pragma unroll
                for (int qf = 0; qf < 2; qf++)
                    sc[qf][nf] = mfma16(qa[qf][ks], kf, sc[qf][nf]);
            }
        }

        // P = exp2(S*C); per-lane partial row-sums (no cross-lane work in loop)
        #pragma unroll
        for (int qf = 0; qf < 2; qf++) {
            #pragma unroll
            for (int r = 0; r < 4; r++) {
                int qr = wid * 32 + qf * 16 + ((lane >> 4) << 2) + r;
                float s4 = 0.f;
                #pragma unroll
                for (int nf = 0; nf < 4; nf++) {
                    float p = __builtin_amdgcn_exp2f(sc[qf][nf][r] * C);
                    s4 += p;
                    int bo = (qr * 128 + (nf * 16 + (lane & 15)) * 2) ^ ((qr & 7) << 4);
                    *(short*)((char*)Pl + bo) = f2bf(p);
                }
                ps[qf][r] += s4;
            }
        }
        // no barrier: each wave's Pl quarter is wave-private; in-wave LDS ordering suffices

        // O += P @ V
        #pragma unroll
        for (int ks = 0; ks < 2; ks++) {
            bf16x8 pa[2];
            #pragma unroll
            for (int qf = 0; qf < 2; qf++) {
                int qrb = wid * 32 + qf * 16 + (lane & 15);
                int bo = (qrb * 128 + ks * 64 + ((lane >> 4) * 16)) ^ ((qrb & 7) << 4);
                pa[qf] = *(const bf16x8*)((const char*)Pl + bo);
            }
            #pragma unroll
            for (int nf = 0; nf < 4; nf++) {
                int dh = nf * 16 + (lane & 15);
                int bo2 = (dh * 128 + ks * 64 + ((lane >> 4) * 16)) ^ ((dh & 7) << 4);
                bf16x8 vf = *(const bf16x8*)((const char*)Vl + bo2);
                #pragma unroll
                for (int qf = 0; qf < 2; qf++)
                    o[qf][nf] = mfma16(pa[qf], vf, o[qf][nf]);
            }
        }
    }

    // final row-sum reduce + output (flat group layout)
    #pragma unroll
    for (int qf = 0; qf < 2; qf++) {
        #pragma unroll
        for (int r = 0; r < 4; r++) {
            float s = ps[qf][r];
            s += __shfl_xor(s, 1);
            s += __shfl_xor(s, 2);
            s += __shfl_xor(s, 4);
            s += __shfl_xor(s, 8);
            float inv = 1.f / s;
            int qr = q0 + wid * 32 + qf * 16 + ((lane >> 4) << 2) + r;
            #pragma unroll
            for (int nf = 0; nf < 4; nf++) {
                int dh = nf * 16 + (lane & 15);
                ctx[base + (size_t)qr * 64 + dh] = f2bf(o[qf][nf][r] * inv);
            }
        }
    }
}

// ---------------- LayerNorm over D=512; one wave per row ----------------
template<int OUTF32>
__global__ __launch_bounds__(256) void ln_k(
        const float* __restrict__ pre, const float* __restrict__ g,
        const float* __restrict__ b, void* __restrict__ out)
{
    int row = blockIdx.x * 4 + (threadIdx.x >> 6);
    int lane = threadIdx.x & 63;
    const float* x = pre + (size_t)row * ND + lane * 8;
    f32x4 a0 = *(const f32x4*)x;
    f32x4 a1 = *(const f32x4*)(x + 4);
    float s = 0.f, sq = 0.f;
    #pragma unroll
    for (int j = 0; j < 4; j++) { s += a0[j]; sq += a0[j] * a0[j]; s += a1[j]; sq += a1[j] * a1[j]; }
    #pragma unroll
    for (int d = 1; d < 64; d <<= 1) { s += __shfl_xor(s, d); sq += __shfl_xor(sq, d); }
    float mean = s * (1.f / ND);
    float var = sq * (1.f / ND) - mean * mean;
    float rstd = rsqrtf(var + 1e-5f);
    const float* gp = g + lane * 8;
    const float* bp = b + lane * 8;
    if (OUTF32) {
        float* op = (float*)out + (size_t)row * ND + lane * 8;
        f32x4 r0, r1;
        #pragma unroll
        for (int j = 0; j < 4; j++) {
            r0[j] = (a0[j] - mean) * rstd * gp[j] + bp[j];
            r1[j] = (a1[j] - mean) * rstd * gp[4 + j] + bp[4 + j];
        }
        *(f32x4*)op = r0;
        *(f32x4*)(op + 4) = r1;
    } else {
        bf16x8 rr;
        #pragma unroll
        for (int j = 0; j < 4; j++) {
            rr[j]     = f2bf((a0[j] - mean) * rstd * gp[j] + bp[j]);
            rr[4 + j] = f2bf((a1[j] - mean) * rstd * gp[4 + j] + bp[4 + j]);
        }
        *(bf16x8*)((short*)out + (size_t)row * ND + lane * 8) = rr;
    }
}

extern "C" void kernel_launch(void* const* d_in, const int* in_sizes, int n_in,
                              void* d_out, int out_size, void* d_ws, size_t ws_size,
                              hipStream_t stream)
{
    (void)in_sizes; (void)n_in; (void)out_size; (void)ws_size;
    const float* x   = (const float*)d_in[0];
    const float* pe  = (const float*)d_in[1];
    const float* Wq  = (const float*)d_in[2];
    const float* bq  = (const float*)d_in[3];
    const float* Wk  = (const float*)d_in[4];
    const float* bk  = (const float*)d_in[5];
    const float* Wv  = (const float*)d_in[6];
    const float* bv  = (const float*)d_in[7];
    const float* Wo  = (const float*)d_in[8];
    const float* bo  = (const float*)d_in[9];
    const float* g1  = (const float*)d_in[10];
    const float* be1 = (const float*)d_in[11];
    const float* W1  = (const float*)d_in[12];
    const float* b1  = (const float*)d_in[13];
    const float* W2  = (const float*)d_in[14];
    const float* b2  = (const float*)d_in[15];
    const float* g2  = (const float*)d_in[16];
    const float* be2 = (const float*)d_in[17];

    char* ws = (char*)d_ws;
    const size_t MB = 1048576;
    short* WT   = (short*)(ws);                  // 16 MiB weights (persistent)
    short* XB   = (short*)(ws + 16 * MB);        // activation bf16
    short* QB   = (short*)(ws + 32 * MB);        // Q  | later AB (post-LN1)
    short* KB   = (short*)(ws + 48 * MB);        // K  \ later PR f32 (48..80)
    short* VB   = (short*)(ws + 64 * MB);        // V  /
    short* VTb  = (short*)(ws + 80 * MB);        // V^T \ later HB (80..112)
    short* CT   = (short*)(ws + 96 * MB);        // ctx /
    float* BQKV = (float*)(ws + 112 * MB);       // packed qkv bias (24 KiB)
    short* AB   = QB;
    float* PR   = (float*)KB;
    short* HB   = VTb;

    // weights: convert + transpose (per launch; graph-capture safe)
    convT_k<<<dim3((NL*ND*ND + 255) / 256), 256, 0, stream>>>(Wq, WT, ND, ND, 0,       NL*ND*ND);
    convT_k<<<dim3((NL*ND*ND + 255) / 256), 256, 0, stream>>>(Wk, WT, ND, ND, 262144,  NL*ND*ND);
    convT_k<<<dim3((NL*ND*ND + 255) / 256), 256, 0, stream>>>(Wv, WT, ND, ND, 524288,  NL*ND*ND);
    convT_k<<<dim3((NL*ND*ND + 255) / 256), 256, 0, stream>>>(Wo, WT, ND, ND, 786432,  NL*ND*ND);
    convT_k<<<dim3((NL*ND*NF + 255) / 256), 256, 0, stream>>>(W1, WT, ND, NF, 1048576, NL*ND*NF);
    convT_k<<<dim3((NL*NF*ND + 255) / 256), 256, 0, stream>>>(W2, WT, NF, ND, 1572864, NL*NF*ND);
    biaspack_k<<<dim3(24), 256, 0, stream>>>(bq, bk, bv, BQKV);

    addpe_k<<<dim3(4096), 256, 0, stream>>>(x, pe, XB);

    for (int l = 0; l < NL; l++) {
        const short* wl = WT + (size_t)l * WLSTRIDE;
        // fused QKV projection: (16384,512) x (512,1536), split outputs
        gemm_bt<0><<<dim3(12, 128), 256, 0, stream>>>(XB, wl, BQKV + l*1536, nullptr,
                                                      QB, KB, VB, NM, 1536, ND);
        vtrans_k<<<dim3(8, 256), 256, 0, stream>>>(VB, VTb);
        attn_k<<<dim3(4, 256), 256, 0, stream>>>(QB, KB, VTb, CT);
        gemm_bt<2><<<dim3(4, 128), 256, 0, stream>>>(CT, wl + 786432, bo + l*ND, XB,
                                                     PR, nullptr, nullptr, NM, ND, ND);
        ln_k<0><<<dim3(4096), 256, 0, stream>>>(PR, g1 + l*ND, be1 + l*ND, AB);
        gemm_bt<1><<<dim3(8, 128), 256, 0, stream>>>(AB, wl + 1048576, b1 + l*NF, nullptr,
                                                     HB, nullptr, nullptr, NM, NF, ND);
        gemm_bt<2><<<dim3(4, 128), 256, 0, stream>>>(HB, wl + 1572864, b2 + l*ND, AB,
                                                     PR, nullptr, nullptr, NM, ND, NF);
        if (l < NL - 1)
            ln_k<0><<<dim3(4096), 256, 0, stream>>>(PR, g2 + l*ND, be2 + l*ND, XB);
        else
            ln_k<1><<<dim3(4096), 256, 0, stream>>>(PR, g2 + l*ND, be2 + l*ND, (float*)d_out);
    }
}

// Round 4
// 780.566 us; speedup vs baseline: 1.4319x; 1.1634x over previous
//
#include <hip/hip_runtime.h>
#include <stdint.h>

// Transformer encoder: B=32 S=512 D=512 H=8 L=4 FFN=1024 DH=64
#define NB 32
#define NS 512
#define ND 512
#define NH 8
#define NL 4
#define NF 1024
#define NDH 64
#define NM (NB*NS)          // 16384 rows
#define WLSTRIDE 2097152    // bf16 elems per layer in transposed weight pack

typedef __attribute__((ext_vector_type(8))) short bf16x8;
typedef __attribute__((ext_vector_type(4))) short s16x4;
typedef __attribute__((ext_vector_type(4))) float f32x4;

#define VM0  asm volatile("s_waitcnt vmcnt(0)" ::: "memory")
#define VM4  asm volatile("s_waitcnt vmcnt(4)" ::: "memory")
#define VM8  asm volatile("s_waitcnt vmcnt(8)" ::: "memory")
#define SCHB __builtin_amdgcn_sched_barrier(0)
#define SB   __builtin_amdgcn_s_barrier()

__device__ __forceinline__ short f2bf(float f) {
    union { float f; uint32_t u; } v; v.f = f;
    uint32_t r = (v.u + 0x7FFFu + ((v.u >> 16) & 1u)) >> 16;
    return (short)r;
}
__device__ __forceinline__ float bf2f(short s) {
    union { uint32_t u; float f; } v; v.u = ((uint32_t)(uint16_t)s) << 16;
    return v.f;
}
__device__ __forceinline__ f32x4 mfma16(bf16x8 a, bf16x8 b, f32x4 c) {
    return __builtin_amdgcn_mfma_f32_16x16x32_bf16(a, b, c, 0, 0, 0);
}
__device__ __forceinline__ void gld16(const void* g, void* l) {
    __builtin_amdgcn_global_load_lds(
        (const __attribute__((address_space(1))) void*)g,
        (__attribute__((address_space(3))) void*)l, 16, 0, 0);
}
// bijective XCD-chunked swizzle (m204); requires gx*gy % 8 == 0
__device__ __forceinline__ void xcd_swz(int& bx, int& by, int gx, int gy) {
    int n = gx * gy;
    int f = by * gx + bx;
    int q = n >> 3;
    int xcd = f & 7, idx = f >> 3;
    int s = xcd * q + idx;
    bx = s % gx; by = s / gx;
}

// ------- weight convert+transpose, LDS-tiled: W(L,K,N) f32 -> Wt(N,K) bf16 @woff ---
__global__ __launch_bounds__(256) void convT_k(const float* __restrict__ src,
        short* __restrict__ dst, int K, int N, int woff)
{
    __shared__ float T[64][65];
    int tk = K >> 6, tn = N >> 6;
    int bid = blockIdx.x;
    int l = bid / (tk * tn), rb = bid % (tk * tn);
    int k0 = (rb / tn) << 6, n0 = (rb % tn) << 6;
    const float* s = src + (size_t)l * K * N;
    short* d = dst + (size_t)l * WLSTRIDE + woff;
    int tr = threadIdx.x >> 4, tc = threadIdx.x & 15;
    #pragma unroll
    for (int p = 0; p < 4; p++) {
        int row = p * 16 + tr;
        f32x4 v = *(const f32x4*)(s + (size_t)(k0 + row) * N + n0 + tc * 4);
        #pragma unroll
        for (int j = 0; j < 4; j++) T[row][tc * 4 + j] = v[j];
    }
    __syncthreads();
    #pragma unroll
    for (int p = 0; p < 4; p++) {
        int nrow = p * 16 + tr;
        s16x4 w;
        #pragma unroll
        for (int j = 0; j < 4; j++) w[j] = f2bf(T[tc * 4 + j][nrow]);
        *(s16x4*)(d + (size_t)(n0 + nrow) * K + k0 + tc * 4) = w;
    }
}

// ---------------- bias pack: [bq|bk|bv] per layer -> (L,1536) f32 ----------------
__global__ __launch_bounds__(256) void biaspack_k(const float* __restrict__ bq,
        const float* __restrict__ bk, const float* __restrict__ bv, float* __restrict__ out)
{
    int i = blockIdx.x * 256 + threadIdx.x;
    if (i >= NL * 1536) return;
    int l = i / 1536, j = i - l * 1536;
    float v = (j < 512) ? bq[l * 512 + j] : (j < 1024) ? bk[l * 512 + j - 512]
                                                       : bv[l * 512 + j - 1024];
    out[i] = v;
}

// ---------------- x + pe -> bf16 ----------------
__global__ __launch_bounds__(256) void addpe_k(const float* __restrict__ x,
        const float* __restrict__ pe, short* __restrict__ X)
{
    size_t i = ((size_t)blockIdx.x * 256 + threadIdx.x) * 8;
    size_t sd = i % (size_t)(NS * ND);
    f32x4 a0 = *(const f32x4*)(x + i);
    f32x4 a1 = *(const f32x4*)(x + i + 4);
    f32x4 p0 = *(const f32x4*)(pe + sd);
    f32x4 p1 = *(const f32x4*)(pe + sd + 4);
    bf16x8 r;
    #pragma unroll
    for (int j = 0; j < 4; j++) { r[j] = f2bf(a0[j] + p0[j]); r[4 + j] = f2bf(a1[j] + p1[j]); }
    *(bf16x8*)(X + i) = r;
}

// ------- GEMM: C = A(M,K) @ Bt(N,K)^T + bias; BK=64, double-buffered pipeline -------
// EPI 0: QKV split -> C0/C1/C2 bf16 (stride 512) by col segment
// EPI 1: bf16 out (bias+relu), stride N. EPI 2: f32 out (bias + bf16 residual), stride N.
template<int EPI>
__global__ __launch_bounds__(256) void gemm_bt(
        const short* __restrict__ A, const short* __restrict__ Bt,
        const float* __restrict__ bias, const short* __restrict__ res,
        void* __restrict__ C0, void* __restrict__ C1, void* __restrict__ C2,
        int M, int N, int K)
{
    __shared__ __align__(16) short Al[16384];   // 2 x [128][64] bf16, XOR-swizzled
    __shared__ __align__(16) short Bl[16384];
    const int tid = threadIdx.x;
    const int wid = tid >> 6, lane = tid & 63;
    int bx = blockIdx.x, by = blockIdx.y;
    xcd_swz(bx, by, gridDim.x, gridDim.y);
    const int m0 = by * 128, n0 = bx * 128;
    const int wr = wid >> 1, wc = wid & 1;

    f32x4 acc[4][4];
    f32x4 zz = {0.f, 0.f, 0.f, 0.f};
    #pragma unroll
    for (int i = 0; i < 4; i++)
        #pragma unroll
        for (int j = 0; j < 4; j++) acc[i][j] = zz;

    const size_t rk = (size_t)K * 2;
    const char* Ab = (const char*)A + (size_t)m0 * rk;
    const char* Bb = (const char*)Bt + (size_t)n0 * rk;

    // per-thread staging coords (4 chunks of 16B per matrix)
    int srow[4], scol[4];
    #pragma unroll
    for (int c = 0; c < 4; c++) {
        int p = c * 4096 + tid * 16;
        int l = p ^ (((p >> 7) & 7) << 4);
        srow[c] = l >> 7;  scol[c] = l & 127;
    }

    auto stage = [&](int dofs, int kt) {   // dofs: byte offset of buffer half
        size_t kb = (size_t)(kt << 6) * 2;
        #pragma unroll
        for (int c = 0; c < 4; c++)
            gld16(Ab + (size_t)srow[c] * rk + kb + scol[c],
                  (char*)Al + dofs + c * 4096 + wid * 1024);
        #pragma unroll
        for (int c = 0; c < 4; c++)
            gld16(Bb + (size_t)srow[c] * rk + kb + scol[c],
                  (char*)Bl + dofs + c * 4096 + wid * 1024);
    };
    auto compute = [&](int dofs) {
        #pragma unroll
        for (int ks = 0; ks < 2; ks++) {
            bf16x8 af[4], bfr[4];
            #pragma unroll
            for (int mf = 0; mf < 4; mf++) {
                int row = wr * 64 + mf * 16 + (lane & 15);
                int off = (row * 128 + ks * 64 + ((lane >> 4) * 16)) ^ ((row & 7) << 4);
                af[mf] = *(const bf16x8*)((const char*)Al + dofs + off);
            }
            #pragma unroll
            for (int nf = 0; nf < 4; nf++) {
                int row = wc * 64 + nf * 16 + (lane & 15);
                int off = (row * 128 + ks * 64 + ((lane >> 4) * 16)) ^ ((row & 7) << 4);
                bfr[nf] = *(const bf16x8*)((const char*)Bl + dofs + off);
            }
            #pragma unroll
            for (int mf = 0; mf < 4; mf++)
                #pragma unroll
                for (int nf = 0; nf < 4; nf++)
                    acc[mf][nf] = mfma16(af[mf], bfr[nf], acc[mf][nf]);
        }
    };

    const int nt = K >> 6;          // 8 or 16 (even)
    stage(0, 0);
    stage(16384, 1);
    VM8; SCHB; SB;
    for (int t = 0; t < nt; t += 2) {
        compute(0);
        SB;                                     // all waves done reading buf0
        if (t + 2 < nt) { stage(0, t + 2); VM8; } else VM0;   // buf1 ready
        SCHB; SB;
        compute(16384);
        SB;                                     // all waves done reading buf1
        if (t + 3 < nt) { stage(16384, t + 3); VM8; } else VM0;  // buf0 ready
        SCHB; SB;
    }

    // output routing
    void* outp;
    int colbase, ostride;
    if (EPI == 0) {
        int seg = n0 >> 9;
        outp = (seg == 0) ? C0 : (seg == 1) ? C1 : C2;
        colbase = n0 & 511; ostride = 512;
    } else {
        outp = C0; colbase = n0; ostride = N;
    }

    #pragma unroll
    for (int mf = 0; mf < 4; mf++) {
        #pragma unroll
        for (int nf = 0; nf < 4; nf++) {
            int colg = n0 + wc * 64 + nf * 16 + (lane & 15);       // bias index
            int col  = colbase + wc * 64 + nf * 16 + (lane & 15);  // output col
            float bi = bias[colg];
            #pragma unroll
            for (int r = 0; r < 4; r++) {
                int row = m0 + wr * 64 + mf * 16 + ((lane >> 4) << 2) + r;
                float v = acc[mf][nf][r] + bi;
                if (EPI == 0) {
                    ((short*)outp)[(size_t)row * 512 + col] = f2bf(v);
                } else if (EPI == 1) {
                    ((short*)outp)[(size_t)row * ostride + col] = f2bf(fmaxf(v, 0.f));
                } else {
                    v += bf2f(res[(size_t)row * ostride + col]);
                    ((float*)outp)[(size_t)row * ostride + col] = v;
                }
            }
        }
    }
}

// ---------------- V transpose (flat-group view): VB(g,kv,dh) -> VT(g,dh,kv) --------
__global__ __launch_bounds__(256) void vtrans_k(const short* __restrict__ V,
        short* __restrict__ VT)
{
    __shared__ short T[64][65];
    const int tid = threadIdx.x;
    const int r0 = blockIdx.x * 64, g = blockIdx.y;
    const size_t base = (size_t)g * 32768;
    #pragma unroll
    for (int rep = 0; rep < 2; rep++) {
        int chunk = rep * 256 + tid;
        int sr = chunk >> 3, c8 = (chunk & 7) * 8;
        bf16x8 v = *(const bf16x8*)(V + base + (size_t)(r0 + sr) * 64 + c8);
        #pragma unroll
        for (int j = 0; j < 8; j++) T[sr][c8 + j] = v[j];
    }
    __syncthreads();
    #pragma unroll
    for (int rep = 0; rep < 2; rep++) {
        int chunk = rep * 256 + tid;
        int dh = chunk >> 3, c8 = (chunk & 7) * 8;
        bf16x8 w;
        #pragma unroll
        for (int j = 0; j < 8; j++) w[j] = T[c8 + j][dh];
        *(bf16x8*)(VT + base + (size_t)dh * 512 + r0 + c8) = w;
    }
}

// ------- flash attention, flat (256,512,64) groups, QBLK=128, K/V dbuf pipeline -----
__global__ __launch_bounds__(256) void attn_k(
        const short* __restrict__ Q, const short* __restrict__ Kb,
        const short* __restrict__ VT, short* __restrict__ ctx)
{
    __shared__ __align__(16) short Kl[8192];   // 2 x [64 kv][64 dh] swizzled
    __shared__ __align__(16) short Vl[8192];   // 2 x [64 dh][64 kv] swizzled
    __shared__ __align__(16) short Pl[8192];   // [128 q][64 kv] swizzled (wave-private quarters)
    const int tid = threadIdx.x, wid = tid >> 6, lane = tid & 63;
    int bx = blockIdx.x, by = blockIdx.y;
    xcd_swz(bx, by, gridDim.x, gridDim.y);
    const int g = by, q0 = bx * 128;
    const size_t base = (size_t)g * 32768;
    const float C = 0.18033688f;               // 0.125 * log2(e)

    // Q fragments: wave wid owns q rows q0+wid*32 .. +32 (2 frags of 16)
    bf16x8 qa[2][2];
    #pragma unroll
    for (int qf = 0; qf < 2; qf++)
        #pragma unroll
        for (int ks = 0; ks < 2; ks++)
            qa[qf][ks] = *(const bf16x8*)(Q + base
                + (size_t)(q0 + wid * 32 + qf * 16 + (lane & 15)) * 64
                + ks * 32 + ((lane >> 4) * 8));

    f32x4 o[2][4];
    float ps[2][4];
    f32x4 zz = {0.f, 0.f, 0.f, 0.f};
    #pragma unroll
    for (int qf = 0; qf < 2; qf++) {
        #pragma unroll
        for (int nf = 0; nf < 4; nf++) o[qf][nf] = zz;
        #pragma unroll
        for (int r = 0; r < 4; r++) ps[qf][r] = 0.f;
    }

    const char* Kbase = (const char*)(Kb + base);   // K tile kt: contiguous 8KB at kt*8192
    const char* Vbase = (const char*)(VT + base);   // V tile: rows dh (1024B), cols kt*128B

    int ksp[2], srow[2], scol[2];
    #pragma unroll
    for (int c = 0; c < 2; c++) {
        int p = c * 4096 + tid * 16;
        ksp[c] = p ^ (((p >> 7) & 7) << 4);
        srow[c] = ksp[c] >> 7;  scol[c] = ksp[c] & 127;
    }

    auto stage = [&](int dofs, int kt) {
        #pragma unroll
        for (int c = 0; c < 2; c++)
            gld16(Kbase + (size_t)kt * 8192 + ksp[c],
                  (char*)Kl + dofs + c * 4096 + wid * 1024);
        #pragma unroll
        for (int c = 0; c < 2; c++)
            gld16(Vbase + (size_t)srow[c] * 1024 + kt * 128 + scol[c],
                  (char*)Vl + dofs + c * 4096 + wid * 1024);
    };

    auto tile = [&](int dofs) {
        // S = Q @ K^T
        f32x4 sc[2][4];
        #pragma unroll
        for (int qf = 0; qf < 2; qf++)
            #pragma unroll
            for (int nf = 0; nf < 4; nf++) sc[qf][nf] = zz;
        #pragma unroll
        for (int ks = 0; ks < 2; ks++) {
            #pragma unroll
            for (int nf = 0; nf < 4; nf++) {
                int kvr = nf * 16 + (lane & 15);
                int bo = ((kvr * 128 + ks * 64 + ((lane >> 4) * 16)) ^ ((kvr & 7) << 4)) + dofs;
                bf16x8 kf = *(const bf16x8*)((const char*)Kl + bo);
                #pragma unroll
                for (int qf = 0; qf < 2; qf++)
                    sc[qf][nf] = mfma16(qa[qf][ks], kf, sc[qf][nf]);
            }
        }
        // P = exp2(S*C); per-lane partial row-sums
        #pragma unroll
        for (int qf = 0; qf < 2; qf++) {
            #pragma unroll
            for (int r = 0; r < 4; r++) {
                int qr = wid * 32 + qf * 16 + ((lane >> 4) << 2) + r;
                float s4 = 0.f;
                #pragma unroll
                for (int nf = 0; nf < 4; nf++) {
                    float p = __builtin_amdgcn_exp2f(sc[qf][nf][r] * C);
                    s4 += p;
                    int bo = (qr * 128 + (nf * 16 + (lane & 15)) * 2) ^ ((qr & 7) << 4);
                    *(short*)((char*)Pl + bo) = f2bf(p);
                }
                ps[qf][r] += s4;
            }
        }
        // O += P @ V (Pl wave-private; in-wave LDS ordering suffices)
        #pragma unroll
        for (int ks = 0; ks < 2; ks++) {
            bf16x8 pa[2];
            #pragma unroll
            for (int qf = 0; qf < 2; qf++) {
                int qrb = wid * 32 + qf * 16 + (lane & 15);
                int bo = (qrb * 128 + ks * 64 + ((lane >> 4) * 16)) ^ ((qrb & 7) << 4);
                pa[qf] = *(const bf16x8*)((const char*)Pl + bo);
            }
            #pragma unroll
            for (int nf = 0; nf < 4; nf++) {
                int dh = nf * 16 + (lane & 15);
                int bo2 = ((dh * 128 + ks * 64 + ((lane >> 4) * 16)) ^ ((dh & 7) << 4)) + dofs;
                bf16x8 vf = *(const bf16x8*)((const char*)Vl + bo2);
                #pragma unroll
                for (int qf = 0; qf < 2; qf++)
                    o[qf][nf] = mfma16(pa[qf], vf, o[qf][nf]);
            }
        }
    };

    stage(0, 0);
    stage(8192, 1);
    VM4; SCHB; SB;
    for (int kt = 0; kt < 8; kt += 2) {
        tile(0);
        SB;
        if (kt + 2 < 8) { stage(0, kt + 2); VM4; } else VM0;
        SCHB; SB;
        tile(8192);
        SB;
        if (kt + 3 < 8) { stage(8192, kt + 3); VM4; } else VM0;
        SCHB; SB;
    }

    // final row-sum reduce + output (flat group layout)
    #pragma unroll
    for (int qf = 0; qf < 2; qf++) {
        #pragma unroll
        for (int r = 0; r < 4; r++) {
            float s = ps[qf][r];
            s += __shfl_xor(s, 1);
            s += __shfl_xor(s, 2);
            s += __shfl_xor(s, 4);
            s += __shfl_xor(s, 8);
            float inv = 1.f / s;
            int qr = q0 + wid * 32 + qf * 16 + ((lane >> 4) << 2) + r;
            #pragma unroll
            for (int nf = 0; nf < 4; nf++) {
                int dh = nf * 16 + (lane & 15);
                ctx[base + (size_t)qr * 64 + dh] = f2bf(o[qf][nf][r] * inv);
            }
        }
    }
}

// ---------------- LayerNorm over D=512; one wave per row ----------------
template<int OUTF32>
__global__ __launch_bounds__(256) void ln_k(
        const float* __restrict__ pre, const float* __restrict__ g,
        const float* __restrict__ b, void* __restrict__ out)
{
    int row = blockIdx.x * 4 + (threadIdx.x >> 6);
    int lane = threadIdx.x & 63;
    const float* x = pre + (size_t)row * ND + lane * 8;
    f32x4 a0 = *(const f32x4*)x;
    f32x4 a1 = *(const f32x4*)(x + 4);
    float s = 0.f, sq = 0.f;
    #pragma unroll
    for (int j = 0; j < 4; j++) { s += a0[j]; sq += a0[j] * a0[j]; s += a1[j]; sq += a1[j] * a1[j]; }
    #pragma unroll
    for (int d = 1; d < 64; d <<= 1) { s += __shfl_xor(s, d); sq += __shfl_xor(sq, d); }
    float mean = s * (1.f / ND);
    float var = sq * (1.f / ND) - mean * mean;
    float rstd = rsqrtf(var + 1e-5f);
    const float* gp = g + lane * 8;
    const float* bp = b + lane * 8;
    if (OUTF32) {
        float* op = (float*)out + (size_t)row * ND + lane * 8;
        f32x4 r0, r1;
        #pragma unroll
        for (int j = 0; j < 4; j++) {
            r0[j] = (a0[j] - mean) * rstd * gp[j] + bp[j];
            r1[j] = (a1[j] - mean) * rstd * gp[4 + j] + bp[4 + j];
        }
        *(f32x4*)op = r0;
        *(f32x4*)(op + 4) = r1;
    } else {
        bf16x8 rr;
        #pragma unroll
        for (int j = 0; j < 4; j++) {
            rr[j]     = f2bf((a0[j] - mean) * rstd * gp[j] + bp[j]);
            rr[4 + j] = f2bf((a1[j] - mean) * rstd * gp[4 + j] + bp[4 + j]);
        }
        *(bf16x8*)((short*)out + (size_t)row * ND + lane * 8) = rr;
    }
}

extern "C" void kernel_launch(void* const* d_in, const int* in_sizes, int n_in,
                              void* d_out, int out_size, void* d_ws, size_t ws_size,
                              hipStream_t stream)
{
    (void)in_sizes; (void)n_in; (void)out_size; (void)ws_size;
    const float* x   = (const float*)d_in[0];
    const float* pe  = (const float*)d_in[1];
    const float* Wq  = (const float*)d_in[2];
    const float* bq  = (const float*)d_in[3];
    const float* Wk  = (const float*)d_in[4];
    const float* bk  = (const float*)d_in[5];
    const float* Wv  = (const float*)d_in[6];
    const float* bv  = (const float*)d_in[7];
    const float* Wo  = (const float*)d_in[8];
    const float* bo  = (const float*)d_in[9];
    const float* g1  = (const float*)d_in[10];
    const float* be1 = (const float*)d_in[11];
    const float* W1  = (const float*)d_in[12];
    const float* b1  = (const float*)d_in[13];
    const float* W2  = (const float*)d_in[14];
    const float* b2  = (const float*)d_in[15];
    const float* g2  = (const float*)d_in[16];
    const float* be2 = (const float*)d_in[17];

    char* ws = (char*)d_ws;
    const size_t MB = 1048576;
    short* WT   = (short*)(ws);                  // 16 MiB weights (persistent)
    short* XB   = (short*)(ws + 16 * MB);        // activation bf16
    short* QB   = (short*)(ws + 32 * MB);        // Q  | later AB (post-LN1)
    short* KB   = (short*)(ws + 48 * MB);        // K  \ later PR f32 (48..80)
    short* VB   = (short*)(ws + 64 * MB);        // V  /
    short* VTb  = (short*)(ws + 80 * MB);        // V^T \ later HB (80..112)
    short* CT   = (short*)(ws + 96 * MB);        // ctx /
    float* BQKV = (float*)(ws + 112 * MB);       // packed qkv bias (24 KiB)
    short* AB   = QB;
    float* PR   = (float*)KB;
    short* HB   = VTb;

    // weights: convert + transpose (tiled, coalesced)
    convT_k<<<dim3(NL*8*8),  256, 0, stream>>>(Wq, WT, ND, ND, 0);
    convT_k<<<dim3(NL*8*8),  256, 0, stream>>>(Wk, WT, ND, ND, 262144);
    convT_k<<<dim3(NL*8*8),  256, 0, stream>>>(Wv, WT, ND, ND, 524288);
    convT_k<<<dim3(NL*8*8),  256, 0, stream>>>(Wo, WT, ND, ND, 786432);
    convT_k<<<dim3(NL*8*16), 256, 0, stream>>>(W1, WT, ND, NF, 1048576);
    convT_k<<<dim3(NL*16*8), 256, 0, stream>>>(W2, WT, NF, ND, 1572864);
    biaspack_k<<<dim3(24), 256, 0, stream>>>(bq, bk, bv, BQKV);

    addpe_k<<<dim3(4096), 256, 0, stream>>>(x, pe, XB);

    for (int l = 0; l < NL; l++) {
        const short* wl = WT + (size_t)l * WLSTRIDE;
        // fused QKV projection: (16384,512) x (512,1536), split outputs
        gemm_bt<0><<<dim3(12, 128), 256, 0, stream>>>(XB, wl, BQKV + l*1536, nullptr,
                                                      QB, KB, VB, NM, 1536, ND);
        vtrans_k<<<dim3(8, 256), 256, 0, stream>>>(VB, VTb);
        attn_k<<<dim3(4, 256), 256, 0, stream>>>(QB, KB, VTb, CT);
        gemm_bt<2><<<dim3(4, 128), 256, 0, stream>>>(CT, wl + 786432, bo + l*ND, XB,
                                                     PR, nullptr, nullptr, NM, ND, ND);
        ln_k<0><<<dim3(4096), 256, 0, stream>>>(PR, g1 + l*ND, be1 + l*ND, AB);
        gemm_bt<1><<<dim3(8, 128), 256, 0, stream>>>(AB, wl + 1048576, b1 + l*NF, nullptr,
                                                     HB, nullptr, nullptr, NM, NF, ND);
        gemm_bt<2><<<dim3(4, 128), 256, 0, stream>>>(HB, wl + 1572864, b2 + l*ND, AB,
                                                     PR, nullptr, nullptr, NM, ND, NF);
        if (l < NL - 1)
            ln_k<0><<<dim3(4096), 256, 0, stream>>>(PR, g2 + l*ND, be2 + l*ND, XB);
        else
            ln_k<1><<<dim3(4096), 256, 0, stream>>>(PR, g2 + l*ND, be2 + l*ND, (float*)d_out);
    }
}

// Round 7
// 759.957 us; speedup vs baseline: 1.4707x; 1.0271x over previous
//
#include <hip/hip_runtime.h>
#include <stdint.h>

// Transformer encoder: B=32 S=512 D=512 H=8 L=4 FFN=1024 DH=64
#define NB 32
#define NS 512
#define ND 512
#define NH 8
#define NL 4
#define NF 1024
#define NDH 64
#define NM (NB*NS)          // 16384 rows
#define WLSTRIDE 2097152    // bf16 elems per layer in transposed weight pack
#define CSCALE 0.18033688f  // 0.125 * log2(e)

typedef __attribute__((ext_vector_type(8))) short bf16x8;
typedef __attribute__((ext_vector_type(4))) short s16x4;
typedef __attribute__((ext_vector_type(4))) float f32x4;
typedef __attribute__((ext_vector_type(2))) uint32_t u32x2;

#define VM0  asm volatile("s_waitcnt vmcnt(0)" ::: "memory")
#define VM4  asm volatile("s_waitcnt vmcnt(4)" ::: "memory")
#define VM8  asm volatile("s_waitcnt vmcnt(8)" ::: "memory")
#define SCHB __builtin_amdgcn_sched_barrier(0)
#define SB   __builtin_amdgcn_s_barrier()

__device__ __forceinline__ short f2bf(float f) {
    union { float f; uint32_t u; } v; v.f = f;
    uint32_t r = (v.u + 0x7FFFu + ((v.u >> 16) & 1u)) >> 16;
    return (short)r;
}
__device__ __forceinline__ float bf2f(short s) {
    union { uint32_t u; float f; } v; v.u = ((uint32_t)(uint16_t)s) << 16;
    return v.f;
}
__device__ __forceinline__ f32x4 mfma16(bf16x8 a, bf16x8 b, f32x4 c) {
    return __builtin_amdgcn_mfma_f32_16x16x32_bf16(a, b, c, 0, 0, 0);
}
__device__ __forceinline__ void gld16(const void* g, void* l) {
    __builtin_amdgcn_global_load_lds(
        (const __attribute__((address_space(1))) void*)g,
        (__attribute__((address_space(3))) void*)l, 16, 0, 0);
}
__device__ __forceinline__ uint32_t cvtpk(float a, float b) {
    uint32_t w;
    asm("v_cvt_pk_bf16_f32 %0, %1, %2" : "=v"(w) : "v"(a), "v"(b));
    return w;
}
// bijective XCD-chunked swizzle (m204); requires gx*gy % 8 == 0
__device__ __forceinline__ void xcd_swz(int& bx, int& by, int gx, int gy) {
    int n = gx * gy;
    int f = by * gx + bx;
    int q = n >> 3;
    int xcd = f & 7, idx = f >> 3;
    int s = xcd * q + idx;
    bx = s % gx; by = s / gx;
}

// ------- weight convert+transpose, LDS-tiled: W(L,K,N) f32 -> Wt(N,K) bf16 @woff ---
__global__ __launch_bounds__(256) void convT_k(const float* __restrict__ src,
        short* __restrict__ dst, int K, int N, int woff)
{
    __shared__ float T[64][65];
    int tk = K >> 6, tn = N >> 6;
    int bid = blockIdx.x;
    int l = bid / (tk * tn), rb = bid % (tk * tn);
    int k0 = (rb / tn) << 6, n0 = (rb % tn) << 6;
    const float* s = src + (size_t)l * K * N;
    short* d = dst + (size_t)l * WLSTRIDE + woff;
    int tr = threadIdx.x >> 4, tc = threadIdx.x & 15;
    #pragma unroll
    for (int p = 0; p < 4; p++) {
        int row = p * 16 + tr;
        f32x4 v = *(const f32x4*)(s + (size_t)(k0 + row) * N + n0 + tc * 4);
        #pragma unroll
        for (int j = 0; j < 4; j++) T[row][tc * 4 + j] = v[j];
    }
    __syncthreads();
    #pragma unroll
    for (int p = 0; p < 4; p++) {
        int nrow = p * 16 + tr;
        s16x4 w;
        #pragma unroll
        for (int j = 0; j < 4; j++) w[j] = f2bf(T[tc * 4 + j][nrow]);
        *(s16x4*)(d + (size_t)(n0 + nrow) * K + k0 + tc * 4) = w;
    }
}

// ------- bias pack: [bq*CS | bk | bv] per layer -> (L,1536) f32 ----------
__global__ __launch_bounds__(256) void biaspack_k(const float* __restrict__ bq,
        const float* __restrict__ bk, const float* __restrict__ bv, float* __restrict__ out)
{
    int i = blockIdx.x * 256 + threadIdx.x;
    if (i >= NL * 1536) return;
    int l = i / 1536, j = i - l * 1536;
    float v = (j < 512) ? bq[l * 512 + j] * CSCALE
            : (j < 1024) ? bk[l * 512 + j - 512] : bv[l * 512 + j - 1024];
    out[i] = v;
}

// ---------------- x + pe -> bf16 ----------------
__global__ __launch_bounds__(256) void addpe_k(const float* __restrict__ x,
        const float* __restrict__ pe, short* __restrict__ X)
{
    size_t i = ((size_t)blockIdx.x * 256 + threadIdx.x) * 8;
    size_t sd = i % (size_t)(NS * ND);
    f32x4 a0 = *(const f32x4*)(x + i);
    f32x4 a1 = *(const f32x4*)(x + i + 4);
    f32x4 p0 = *(const f32x4*)(pe + sd);
    f32x4 p1 = *(const f32x4*)(pe + sd + 4);
    bf16x8 r;
    #pragma unroll
    for (int j = 0; j < 4; j++) { r[j] = f2bf(a0[j] + p0[j]); r[4 + j] = f2bf(a1[j] + p1[j]); }
    *(bf16x8*)(X + i) = r;
}

// ------- GEMM: C = A(M,K) @ Bt(N,K)^T + bias; BK=64, double-buffered pipeline -------
// EPI 0: QKV split -> C0/C1/C2 bf16 (stride 512); Q segment pre-scaled by CSCALE.
// EPI 1: bf16 out (bias+relu), stride N. EPI 2: f32 out (bias + bf16 residual), stride N.
template<int EPI>
__global__ __launch_bounds__(256) void gemm_bt(
        const short* __restrict__ A, const short* __restrict__ Bt,
        const float* __restrict__ bias, const short* __restrict__ res,
        void* __restrict__ C0, void* __restrict__ C1, void* __restrict__ C2,
        int M, int N, int K)
{
    __shared__ __align__(16) short Al[16384];   // 2 x [128][64] bf16, XOR-swizzled
    __shared__ __align__(16) short Bl[16384];
    const int tid = threadIdx.x;
    const int wid = tid >> 6, lane = tid & 63;
    int bx = blockIdx.x, by = blockIdx.y;
    xcd_swz(bx, by, gridDim.x, gridDim.y);
    const int m0 = by * 128, n0 = bx * 128;
    const int wr = wid >> 1, wc = wid & 1;

    f32x4 acc[4][4];
    f32x4 zz = {0.f, 0.f, 0.f, 0.f};
    #pragma unroll
    for (int i = 0; i < 4; i++)
        #pragma unroll
        for (int j = 0; j < 4; j++) acc[i][j] = zz;

    const size_t rk = (size_t)K * 2;
    const char* Ab = (const char*)A + (size_t)m0 * rk;
    const char* Bb = (const char*)Bt + (size_t)n0 * rk;

    // per-thread staging coords (4 chunks of 16B per matrix)
    int srow[4], scol[4];
    #pragma unroll
    for (int c = 0; c < 4; c++) {
        int p = c * 4096 + tid * 16;
        int l = p ^ (((p >> 7) & 7) << 4);
        srow[c] = l >> 7;  scol[c] = l & 127;
    }

    auto stage = [&](int dofs, int kt) {   // dofs: byte offset of buffer half
        size_t kb = (size_t)(kt << 6) * 2;
        #pragma unroll
        for (int c = 0; c < 4; c++)
            gld16(Ab + (size_t)srow[c] * rk + kb + scol[c],
                  (char*)Al + dofs + c * 4096 + wid * 1024);
        #pragma unroll
        for (int c = 0; c < 4; c++)
            gld16(Bb + (size_t)srow[c] * rk + kb + scol[c],
                  (char*)Bl + dofs + c * 4096 + wid * 1024);
    };
    auto compute = [&](int dofs) {
        #pragma unroll
        for (int ks = 0; ks < 2; ks++) {
            bf16x8 af[4], bfr[4];
            #pragma unroll
            for (int mf = 0; mf < 4; mf++) {
                int row = wr * 64 + mf * 16 + (lane & 15);
                int off = (row * 128 + ks * 64 + ((lane >> 4) * 16)) ^ ((row & 7) << 4);
                af[mf] = *(const bf16x8*)((const char*)Al + dofs + off);
            }
            #pragma unroll
            for (int nf = 0; nf < 4; nf++) {
                int row = wc * 64 + nf * 16 + (lane & 15);
                int off = (row * 128 + ks * 64 + ((lane >> 4) * 16)) ^ ((row & 7) << 4);
                bfr[nf] = *(const bf16x8*)((const char*)Bl + dofs + off);
            }
            #pragma unroll
            for (int mf = 0; mf < 4; mf++)
                #pragma unroll
                for (int nf = 0; nf < 4; nf++)
                    acc[mf][nf] = mfma16(af[mf], bfr[nf], acc[mf][nf]);
        }
    };

    const int nt = K >> 6;          // 8 or 16 (even)
    stage(0, 0);
    stage(16384, 1);
    VM8; SCHB; SB;
    for (int t = 0; t < nt; t += 2) {
        compute(0);
        SB;                                     // all waves done reading buf0
        if (t + 2 < nt) { stage(0, t + 2); VM8; } else VM0;   // buf1 ready
        SCHB; SB;
        compute(16384);
        SB;                                     // all waves done reading buf1
        if (t + 3 < nt) { stage(16384, t + 3); VM8; } else VM0;  // buf0 ready
        SCHB; SB;
    }

    // output routing
    int seg = 0;
    void* outp;
    int colbase, ostride;
    if (EPI == 0) {
        seg = n0 >> 9;
        outp = (seg == 0) ? C0 : (seg == 1) ? C1 : C2;
        colbase = n0 & 511; ostride = 512;
    } else {
        outp = C0; colbase = n0; ostride = N;
    }

    #pragma unroll
    for (int mf = 0; mf < 4; mf++) {
        #pragma unroll
        for (int nf = 0; nf < 4; nf++) {
            int colg = n0 + wc * 64 + nf * 16 + (lane & 15);       // bias index
            int col  = colbase + wc * 64 + nf * 16 + (lane & 15);  // output col
            float bi = bias[colg];
            #pragma unroll
            for (int r = 0; r < 4; r++) {
                int row = m0 + wr * 64 + mf * 16 + ((lane >> 4) << 2) + r;
                float v;
                if (EPI == 0 && seg == 0) v = acc[mf][nf][r] * CSCALE + bi; // Q pre-scaled
                else                      v = acc[mf][nf][r] + bi;
                if (EPI == 0) {
                    ((short*)outp)[(size_t)row * 512 + col] = f2bf(v);
                } else if (EPI == 1) {
                    ((short*)outp)[(size_t)row * ostride + col] = f2bf(fmaxf(v, 0.f));
                } else {
                    v += bf2f(res[(size_t)row * ostride + col]);
                    ((float*)outp)[(size_t)row * ostride + col] = v;
                }
            }
        }
    }
}

// ---------------- V transpose (flat-group view): VB(g,kv,dh) -> VT(g,dh,kv) --------
__global__ __launch_bounds__(256) void vtrans_k(const short* __restrict__ V,
        short* __restrict__ VT)
{
    __shared__ short T[64][65];
    const int tid = threadIdx.x;
    const int r0 = blockIdx.x * 64, g = blockIdx.y;
    const size_t base = (size_t)g * 32768;
    #pragma unroll
    for (int rep = 0; rep < 2; rep++) {
        int chunk = rep * 256 + tid;
        int sr = chunk >> 3, c8 = (chunk & 7) * 8;
        bf16x8 v = *(const bf16x8*)(V + base + (size_t)(r0 + sr) * 64 + c8);
        #pragma unroll
        for (int j = 0; j < 8; j++) T[sr][c8 + j] = v[j];
    }
    __syncthreads();
    #pragma unroll
    for (int rep = 0; rep < 2; rep++) {
        int chunk = rep * 256 + tid;
        int dh = chunk >> 3, c8 = (chunk & 7) * 8;
        bf16x8 w;
        #pragma unroll
        for (int j = 0; j < 8; j++) w[j] = T[c8 + j][dh];
        *(bf16x8*)(VT + base + (size_t)dh * 512 + r0 + c8) = w;
    }
}

// ------- flash attention, flat (256,512,64) groups, QBLK=128, K/V dbuf pipeline -----
// Q pre-scaled by 0.125*log2e. K flat (g,kv,dh); V from VT(g,dh,kv); out ctx flat.
__global__ __launch_bounds__(256) void attn_k(
        const short* __restrict__ Q, const short* __restrict__ Kb,
        const short* __restrict__ VT, short* __restrict__ ctx)
{
    __shared__ __align__(16) short Kl[8192];   // 2 x [64 kv][64 dh], XOR ((row>>2)&7)<<4
    __shared__ __align__(16) short Vl[8192];   // 2 x [64 dh][64 kv], XOR ((row&7))<<4
    __shared__ __align__(16) short Pl[8192];   // [128 q][64 kv], XOR ((qr&7))<<4 (wave-private)
    const int tid = threadIdx.x, wid = tid >> 6, lane = tid & 63;
    int bx = blockIdx.x, by = blockIdx.y;
    xcd_swz(bx, by, gridDim.x, gridDim.y);
    const int g = by, q0 = bx * 128;
    const size_t base = (size_t)g * 32768;

    // Q fragments: wave wid owns q rows q0+wid*32 .. +32 (2 frags of 16)
    bf16x8 qa[2][2];
    #pragma unroll
    for (int qf = 0; qf < 2; qf++)
        #pragma unroll
        for (int ks = 0; ks < 2; ks++)
            qa[qf][ks] = *(const bf16x8*)(Q + base
                + (size_t)(q0 + wid * 32 + qf * 16 + (lane & 15)) * 64
                + ks * 32 + ((lane >> 4) * 8));

    f32x4 o[2][4];
    float ps[2][4];
    f32x4 zz = {0.f, 0.f, 0.f, 0.f};
    #pragma unroll
    for (int qf = 0; qf < 2; qf++) {
        #pragma unroll
        for (int nf = 0; nf < 4; nf++) o[qf][nf] = zz;
        #pragma unroll
        for (int r = 0; r < 4; r++) ps[qf][r] = 0.f;
    }

    const char* Kbase = (const char*)(Kb + base);   // K tile kt: contiguous 8KB at kt*8192
    const char* Vbase = (const char*)(VT + base);   // V tile: rows dh (1024B), cols kt*128B

    int ksp[2], srow[2], scol[2];
    #pragma unroll
    for (int c = 0; c < 2; c++) {
        int p = c * 4096 + tid * 16;
        ksp[c] = p ^ (((p >> 9) & 7) << 4);          // K-side pre-swizzle (row>>2 based)
        int pv = p ^ (((p >> 7) & 7) << 4);          // V-side pre-swizzle (row based)
        srow[c] = pv >> 7;  scol[c] = pv & 127;
    }

    auto stage = [&](int dofs, int kt) {
        #pragma unroll
        for (int c = 0; c < 2; c++)
            gld16(Kbase + (size_t)kt * 8192 + ksp[c],
                  (char*)Kl + dofs + c * 4096 + wid * 1024);
        #pragma unroll
        for (int c = 0; c < 2; c++)
            gld16(Vbase + (size_t)srow[c] * 1024 + kt * 128 + scol[c],
                  (char*)Vl + dofs + c * 4096 + wid * 1024);
    };

    auto tile = [&](int dofs) {
        // S = Q @ K^T ; kv-interleaved fragments: sc[qf][nf] holds kv = 4*(lane&15)+nf
        f32x4 sc[2][4];
        #pragma unroll
        for (int qf = 0; qf < 2; qf++)
            #pragma unroll
            for (int nf = 0; nf < 4; nf++) sc[qf][nf] = zz;
        #pragma unroll
        for (int ks = 0; ks < 2; ks++) {
            #pragma unroll
            for (int nf = 0; nf < 4; nf++) {
                int kvr = (lane & 15) * 4 + nf;
                int bo = (kvr * 128 + ((ks * 64 + ((lane >> 4) * 16)) ^ (((kvr >> 2) & 7) << 4)))
                         + dofs;
                bf16x8 kf = *(const bf16x8*)((const char*)Kl + bo);
                #pragma unroll
                for (int qf = 0; qf < 2; qf++)
                    sc[qf][nf] = mfma16(qa[qf][ks], kf, sc[qf][nf]);
            }
        }

        // P = exp2(S); pack 4 contiguous kv -> one ds_write_b64 per (qf,r)
        #pragma unroll
        for (int qf = 0; qf < 2; qf++) {
            #pragma unroll
            for (int r = 0; r < 4; r++) {
                int qr = wid * 32 + qf * 16 + ((lane >> 4) << 2) + r;
                float e0 = __builtin_amdgcn_exp2f(sc[qf][0][r]);
                float e1 = __builtin_amdgcn_exp2f(sc[qf][1][r]);
                float e2 = __builtin_amdgcn_exp2f(sc[qf][2][r]);
                float e3 = __builtin_amdgcn_exp2f(sc[qf][3][r]);
                ps[qf][r] += (e0 + e1) + (e2 + e3);
                u32x2 w;
                w[0] = cvtpk(e0, e1);
                w[1] = cvtpk(e2, e3);
                int bo = (qr * 128 + (lane & 15) * 8) ^ ((qr & 7) << 4);
                *(u32x2*)((char*)Pl + bo) = w;
            }
        }
        // no barrier: each wave's Pl quarter is wave-private; in-wave LDS ordering suffices

        // O += P @ V
        #pragma unroll
        for (int ks = 0; ks < 2; ks++) {
            bf16x8 pa[2];
            #pragma unroll
            for (int qf = 0; qf < 2; qf++) {
                int qrb = wid * 32 + qf * 16 + (lane & 15);
                int bo = (qrb * 128 + ks * 64 + ((lane >> 4) * 16)) ^ ((qrb & 7) << 4);
                pa[qf] = *(const bf16x8*)((const char*)Pl + bo);
            }
            #pragma unroll
            for (int nf = 0; nf < 4; nf++) {
                int dh = nf * 16 + (lane & 15);
                int bo2 = ((dh * 128 + ks * 64 + ((lane >> 4) * 16)) ^ ((dh & 7) << 4)) + dofs;
                bf16x8 vf = *(const bf16x8*)((const char*)Vl + bo2);
                #pragma unroll
                for (int qf = 0; qf < 2; qf++)
                    o[qf][nf] = mfma16(pa[qf], vf, o[qf][nf]);
            }
        }
    };

    stage(0, 0);
    stage(8192, 1);
    VM4; SCHB; SB;
    for (int kt = 0; kt < 8; kt += 2) {
        tile(0);
        SB;
        if (kt + 2 < 8) { stage(0, kt + 2); VM4; } else VM0;
        SCHB; SB;
        tile(8192);
        SB;
        if (kt + 3 < 8) { stage(8192, kt + 3); VM4; } else VM0;
        SCHB; SB;
    }

    // final row-sum reduce + output (flat group layout)
    #pragma unroll
    for (int qf = 0; qf < 2; qf++) {
        #pragma unroll
        for (int r = 0; r < 4; r++) {
            float s = ps[qf][r];
            s += __shfl_xor(s, 1);
            s += __shfl_xor(s, 2);
            s += __shfl_xor(s, 4);
            s += __shfl_xor(s, 8);
            float inv = 1.f / s;
            int qr = q0 + wid * 32 + qf * 16 + ((lane >> 4) << 2) + r;
            #pragma unroll
            for (int nf = 0; nf < 4; nf++) {
                int dh = nf * 16 + (lane & 15);
                ctx[base + (size_t)qr * 64 + dh] = f2bf(o[qf][nf][r] * inv);
            }
        }
    }
}

// ---------------- LayerNorm over D=512; one wave per row ----------------
template<int OUTF32>
__global__ __launch_bounds__(256) void ln_k(
        const float* __restrict__ pre, const float* __restrict__ g,
        const float* __restrict__ b, void* __restrict__ out)
{
    int row = blockIdx.x * 4 + (threadIdx.x >> 6);
    int lane = threadIdx.x & 63;
    const float* x = pre + (size_t)row * ND + lane * 8;
    f32x4 a0 = *(const f32x4*)x;
    f32x4 a1 = *(const f32x4*)(x + 4);
    float s = 0.f, sq = 0.f;
    #pragma unroll
    for (int j = 0; j < 4; j++) { s += a0[j]; sq += a0[j] * a0[j]; s += a1[j]; sq += a1[j] * a1[j]; }
    #pragma unroll
    for (int d = 1; d < 64; d <<= 1) { s += __shfl_xor(s, d); sq += __shfl_xor(sq, d); }
    float mean = s * (1.f / ND);
    float var = sq * (1.f / ND) - mean * mean;
    float rstd = rsqrtf(var + 1e-5f);
    const float* gp = g + lane * 8;
    const float* bp = b + lane * 8;
    if (OUTF32) {
        float* op = (float*)out + (size_t)row * ND + lane * 8;
        f32x4 r0, r1;
        #pragma unroll
        for (int j = 0; j < 4; j++) {
            r0[j] = (a0[j] - mean) * rstd * gp[j] + bp[j];
            r1[j] = (a1[j] - mean) * rstd * gp[4 + j] + bp[4 + j];
        }
        *(f32x4*)op = r0;
        *(f32x4*)(op + 4) = r1;
    } else {
        bf16x8 rr;
        #pragma unroll
        for (int j = 0; j < 4; j++) {
            rr[j]     = f2bf((a0[j] - mean) * rstd * gp[j] + bp[j]);
            rr[4 + j] = f2bf((a1[j] - mean) * rstd * gp[4 + j] + bp[4 + j]);
        }
        *(bf16x8*)((short*)out + (size_t)row * ND + lane * 8) = rr;
    }
}

extern "C" void kernel_launch(void* const* d_in, const int* in_sizes, int n_in,
                              void* d_out, int out_size, void* d_ws, size_t ws_size,
                              hipStream_t stream)
{
    (void)in_sizes; (void)n_in; (void)out_size; (void)ws_size;
    const float* x   = (const float*)d_in[0];
    const float* pe  = (const float*)d_in[1];
    const float* Wq  = (const float*)d_in[2];
    const float* bq  = (const float*)d_in[3];
    const float* Wk  = (const float*)d_in[4];
    const float* bk  = (const float*)d_in[5];
    const float* Wv  = (const float*)d_in[6];
    const float* bv  = (const float*)d_in[7];
    const float* Wo  = (const float*)d_in[8];
    const float* bo  = (const float*)d_in[9];
    const float* g1  = (const float*)d_in[10];
    const float* be1 = (const float*)d_in[11];
    const float* W1  = (const float*)d_in[12];
    const float* b1  = (const float*)d_in[13];
    const float* W2  = (const float*)d_in[14];
    const float* b2  = (const float*)d_in[15];
    const float* g2  = (const float*)d_in[16];
    const float* be2 = (const float*)d_in[17];

    char* ws = (char*)d_ws;
    const size_t MB = 1048576;
    short* WT   = (short*)(ws);                  // 16 MiB weights (persistent)
    short* XB   = (short*)(ws + 16 * MB);        // activation bf16
    short* QB   = (short*)(ws + 32 * MB);        // Q (pre-scaled) | later AB (post-LN1)
    short* KB   = (short*)(ws + 48 * MB);        // K  \ later PR f32 (48..80)
    short* VB   = (short*)(ws + 64 * MB);        // V  /
    short* VTb  = (short*)(ws + 80 * MB);        // V^T \ later HB (80..112)
    short* CT   = (short*)(ws + 96 * MB);        // ctx /
    float* BQKV = (float*)(ws + 112 * MB);       // packed qkv bias (24 KiB)
    short* AB   = QB;
    float* PR   = (float*)KB;                    // 48..80 (K + V dead post-attn)
    short* HB   = VTb;                           // 80..112 (V^T + ctx dead post O-proj)

    // weights: convert + transpose (tiled, coalesced)
    convT_k<<<dim3(NL*8*8),  256, 0, stream>>>(Wq, WT, ND, ND, 0);
    convT_k<<<dim3(NL*8*8),  256, 0, stream>>>(Wk, WT, ND, ND, 262144);
    convT_k<<<dim3(NL*8*8),  256, 0, stream>>>(Wv, WT, ND, ND, 524288);
    convT_k<<<dim3(NL*8*8),  256, 0, stream>>>(Wo, WT, ND, ND, 786432);
    convT_k<<<dim3(NL*8*16), 256, 0, stream>>>(W1, WT, ND, NF, 1048576);
    convT_k<<<dim3(NL*16*8), 256, 0, stream>>>(W2, WT, NF, ND, 1572864);
    biaspack_k<<<dim3(24), 256, 0, stream>>>(bq, bk, bv, BQKV);

    addpe_k<<<dim3(4096), 256, 0, stream>>>(x, pe, XB);

    for (int l = 0; l < NL; l++) {
        const short* wl = WT + (size_t)l * WLSTRIDE;
        // fused QKV projection: (16384,512) x (512,1536); Q pre-scaled
        gemm_bt<0><<<dim3(12, 128), 256, 0, stream>>>(XB, wl, BQKV + l*1536, nullptr,
                                                      QB, KB, VB, NM, 1536, ND);
        vtrans_k<<<dim3(8, 256), 256, 0, stream>>>(VB, VTb);
        attn_k<<<dim3(4, 256), 256, 0, stream>>>(QB, KB, VTb, CT);
        gemm_bt<2><<<dim3(4, 128), 256, 0, stream>>>(CT, wl + 786432, bo + l*ND, XB,
                                                     PR, nullptr, nullptr, NM, ND, ND);
        ln_k<0><<<dim3(4096), 256, 0, stream>>>(PR, g1 + l*ND, be1 + l*ND, AB);
        gemm_bt<1><<<dim3(8, 128), 256, 0, stream>>>(AB, wl + 1048576, b1 + l*NF, nullptr,
                                                     HB, nullptr, nullptr, NM, NF, ND);
        gemm_bt<2><<<dim3(4, 128), 256, 0, stream>>>(HB, wl + 1572864, b2 + l*ND, AB,
                                                     PR, nullptr, nullptr, NM, ND, NF);
        if (l < NL - 1)
            ln_k<0><<<dim3(4096), 256, 0, stream>>>(PR, g2 + l*ND, be2 + l*ND, XB);
        else
            ln_k<1><<<dim3(4096), 256, 0, stream>>>(PR, g2 + l*ND, be2 + l*ND, (float*)d_out);
    }
}